// Round 1
// baseline (1943.286 us; speedup 1.0000x reference)
//
#include <hip/hip_runtime.h>

static constexpr int DIM   = 256;
static constexpr int NCODE = 8192;
static constexpr int NROWS = 16384;
static constexpr int BM    = 64;
static constexpr int BN    = 64;
static constexpr int APAD  = 68;   // floats; 68*4=272B row stride -> 16B aligned, bank-safe

// ---------------------------------------------------------------------------
// P0: e2[j] = sum_k embed[k][j]^2, serial ascending k, mul-then-add (no fma)
// to mimic XLA's elementwise-square + reduce rounding.
// ---------------------------------------------------------------------------
__global__ __launch_bounds__(256) void e2_kernel(const float* __restrict__ embed,
                                                 float* __restrict__ e2) {
    int j = blockIdx.x * 256 + threadIdx.x;   // 8192 threads, coalesced over j
    float s = 0.f;
    for (int k = 0; k < DIM; ++k) {
        float v = embed[(size_t)k * NCODE + j];
        s = __fadd_rn(s, __fmul_rn(v, v));
    }
    e2[j] = s;
}

// ---------------------------------------------------------------------------
// P1: fused dist + argmin. dist replicated as ((f2 - 2*dot) + e2) in fp32,
// dot = k-ascending single-accumulator FMA chain. Strict < scan ascending
// ==> first-occurrence argmin like jnp.argmin.
// ---------------------------------------------------------------------------
__global__ __launch_bounds__(256, 1) void dist_argmin_kernel(
    const float* __restrict__ x, const float* __restrict__ embed,
    const float* __restrict__ e2g, unsigned int* __restrict__ best_out)
{
    __shared__ float xs[DIM][APAD];   // x tile transposed: xs[k][r]   (69.6 KB)
    __shared__ float es[DIM][BN];     // embed tile:        es[k][c]   (64 KB)
    __shared__ float f2s[BM];

    const int t    = threadIdx.x;
    const int row0 = blockIdx.x * BM;

    // stage x tile transposed (once per block; coalesced float4 reads)
    #pragma unroll
    for (int s = 0; s < 16; ++s) {
        int f  = s * 256 + t;
        int r  = f >> 6;          // 0..63
        int k4 = f & 63;          // float4 index within row
        float4 v = *reinterpret_cast<const float4*>(x + (size_t)(row0 + r) * DIM + k4 * 4);
        xs[k4 * 4 + 0][r] = v.x;
        xs[k4 * 4 + 1][r] = v.y;
        xs[k4 * 4 + 2][r] = v.z;
        xs[k4 * 4 + 3][r] = v.w;
    }

    // register-prefetch B tile 0 (overlaps with xs staging latency)
    float4 breg[16];
    #pragma unroll
    for (int s = 0; s < 16; ++s) {
        int f  = s * 256 + t;
        int k  = f >> 4;
        int c4 = f & 15;
        breg[s] = *reinterpret_cast<const float4*>(embed + (size_t)k * NCODE + c4 * 4);
    }

    __syncthreads();   // xs ready

    // f2 per row: serial ascending, mul-then-add (mimic sum(x*x, axis=1))
    if (t < BM) {
        float s = 0.f;
        for (int k = 0; k < DIM; ++k) {
            float v = xs[k][t];
            s = __fadd_rn(s, __fmul_rn(v, v));
        }
        f2s[t] = s;
    }

    const int rg = t >> 4;    // row group: rows 4*rg .. 4*rg+3
    const int cg = t & 15;    // col group: cols 4*cg .. 4*cg+3 (+n0)

    float    bestd[4];
    unsigned bidx[4];
    #pragma unroll
    for (int i = 0; i < 4; ++i) { bestd[i] = __builtin_inff(); bidx[i] = 0u; }

    for (int n0 = 0; n0 < NCODE; n0 += BN) {
        __syncthreads();   // es free to overwrite (also covers f2s on iter 0)
        #pragma unroll
        for (int s = 0; s < 16; ++s) {
            int f = s * 256 + t;
            *reinterpret_cast<float4*>(&es[0][0] + f * 4) = breg[s];
        }
        __syncthreads();   // es ready

        if (n0 + BN < NCODE) {   // prefetch next tile; latency hidden under compute
            #pragma unroll
            for (int s = 0; s < 16; ++s) {
                int f  = s * 256 + t;
                int k  = f >> 4;
                int c4 = f & 15;
                breg[s] = *reinterpret_cast<const float4*>(
                    embed + (size_t)k * NCODE + (n0 + BN) + c4 * 4);
            }
        }

        float acc[4][4];
        #pragma unroll
        for (int i = 0; i < 4; ++i)
            #pragma unroll
            for (int j = 0; j < 4; ++j) acc[i][j] = 0.f;

        #pragma unroll 4
        for (int k = 0; k < DIM; ++k) {
            float4 a = *reinterpret_cast<const float4*>(&xs[k][rg * 4]);
            float4 b = *reinterpret_cast<const float4*>(&es[k][cg * 4]);
            float av[4] = {a.x, a.y, a.z, a.w};
            float bv[4] = {b.x, b.y, b.z, b.w};
            #pragma unroll
            for (int i = 0; i < 4; ++i)
                #pragma unroll
                for (int j = 0; j < 4; ++j)
                    acc[i][j] = __builtin_fmaf(av[i], bv[j], acc[i][j]);
        }

        // epilogue: dist = (f2 - 2*dot) + e2 ; running argmin (strict <)
        float e2v[4];
        #pragma unroll
        for (int j = 0; j < 4; ++j) e2v[j] = e2g[n0 + cg * 4 + j];
        #pragma unroll
        for (int i = 0; i < 4; ++i) {
            float f2r = f2s[rg * 4 + i];
            #pragma unroll
            for (int j = 0; j < 4; ++j) {
                float d = __fadd_rn(__builtin_fmaf(-2.0f, acc[i][j], f2r), e2v[j]);
                unsigned idx = (unsigned)(n0 + cg * 4 + j);
                if (d < bestd[i]) { bestd[i] = d; bidx[i] = idx; }
            }
        }
    }

    // merge across the 16 lanes sharing the same rows (lane group = l>>4)
    #pragma unroll
    for (int i = 0; i < 4; ++i) {
        float    d   = bestd[i];
        unsigned idx = bidx[i];
        #pragma unroll
        for (int m = 8; m >= 1; m >>= 1) {
            float    od = __shfl_xor(d, m);
            unsigned oi = (unsigned)__shfl_xor((int)idx, m);
            if (od < d || (od == d && oi < idx)) { d = od; idx = oi; }
        }
        bestd[i] = d; bidx[i] = idx;
    }
    if (cg == 0) {
        #pragma unroll
        for (int i = 0; i < 4; ++i)
            best_out[row0 + rg * 4 + i] = bidx[i];
    }
}

// ---------------------------------------------------------------------------
// P2: gather + straight-through + diff accumulation + ind as float.
// One block per row; reads best idx (aliased in ind region), overwrites it.
// ---------------------------------------------------------------------------
__global__ __launch_bounds__(256) void output_kernel(
    const float* __restrict__ x, const float* __restrict__ embed,
    const unsigned int* __restrict__ best_idx,
    float* __restrict__ quant, float* __restrict__ diff, float* __restrict__ ind)
{
    const int row = blockIdx.x;
    const int d   = threadIdx.x;
    const unsigned idx = best_idx[row];

    float xv = x[(size_t)row * DIM + d];
    float q  = embed[(size_t)d * NCODE + idx];   // column gather, L2/L3 resident
    float dq = __fsub_rn(q, xv);
    quant[(size_t)row * DIM + d] = __fadd_rn(xv, dq);   // x + (q - x), as reference

    float c = __fmul_rn(dq, dq);
    #pragma unroll
    for (int off = 32; off >= 1; off >>= 1) c += __shfl_down(c, off);

    __shared__ float partial[4];
    if ((d & 63) == 0) partial[d >> 6] = c;
    __syncthreads();   // also guarantees all lanes read best_idx before overwrite
    if (d == 0) {
        float s = (partial[0] + partial[1]) + (partial[2] + partial[3]);
        atomicAdd(diff, s * (1.25f / 4194304.f));  // (1+BETA) * mean
        ind[row] = (float)idx;                     // overwrite best_idx slot
    }
}

// ---------------------------------------------------------------------------
extern "C" void kernel_launch(void* const* d_in, const int* in_sizes, int n_in,
                              void* d_out, int out_size, void* d_ws, size_t ws_size,
                              hipStream_t stream)
{
    const float* x     = (const float*)d_in[0];   // [16384, 256]
    const float* embed = (const float*)d_in[1];   // [256, 8192]

    float* out   = (float*)d_out;
    float* quant = out;                 // 4194304 floats
    float* diff  = out + 4194304;       // 1 float
    float* ind   = out + 4194305;       // 16384 floats

    // Scratch overlays inside d_out (consumed before being overwritten):
    //  - e2 lives in quant[0..8191]  (P1 reads it; P2 overwrites region after)
    //  - best_idx lives in the ind region as u32 (P2 reads, then overwrites)
    float*        e2       = quant;
    unsigned int* best_idx = (unsigned int*)ind;

    e2_kernel<<<32, 256, 0, stream>>>(embed, e2);
    dist_argmin_kernel<<<256, 256, 0, stream>>>(x, embed, e2, best_idx);
    hipMemsetAsync(diff, 0, sizeof(float), stream);
    output_kernel<<<NROWS, 256, 0, stream>>>(x, embed, best_idx, quant, diff, ind);
}

// Round 2
// 752.076 us; speedup vs baseline: 2.5839x; 2.5839x over previous
//
#include <hip/hip_runtime.h>

static constexpr int DIM   = 256;
static constexpr int NCODE = 8192;
static constexpr int NROWS = 16384;

typedef __bf16 bf16x8 __attribute__((ext_vector_type(8)));
typedef float  f32x4  __attribute__((ext_vector_type(4)));

// ---------------------------------------------------------------------------
// helpers
// ---------------------------------------------------------------------------
__device__ __forceinline__ void gload_lds16(const void* g, void* l) {
    __builtin_amdgcn_global_load_lds(
        (const __attribute__((address_space(1))) void*)g,
        (__attribute__((address_space(3))) void*)l, 16, 0, 0);
}

// insert scalar into sorted top2 (v0<=v1)
__device__ __forceinline__ void top2_insert(float& v0, int& i0, float& v1, int& i1,
                                            float s, int si) {
    if (s < v0) { v1 = v0; i1 = i0; v0 = s; i0 = si; }
    else if (s < v1) { v1 = s; i1 = si; }
}
// merge sorted pair (b0<=b1) into (v0<=v1)
__device__ __forceinline__ void top2_merge(float& v0, int& i0, float& v1, int& i1,
                                           float b0, int bi0, float b1, int bi1) {
    if (b0 < v0) {
        if (b1 < v0) { v0 = b0; i0 = bi0; v1 = b1; i1 = bi1; }
        else         { v1 = v0; i1 = i0;  v0 = b0; i0 = bi0; }
    } else if (b0 < v1) { v1 = b0; i1 = bi0; }
}

// ---------------------------------------------------------------------------
// K0a: x fp32 -> bf16 row-major [16384][256]
// ---------------------------------------------------------------------------
__global__ __launch_bounds__(256) void cvt_x_kernel(const float* __restrict__ x,
                                                    ushort* __restrict__ xb) {
    int i = blockIdx.x * 256 + threadIdx.x;        // 524288 groups of 8
    const float4* xp = (const float4*)x + (size_t)i * 2;
    float4 a = xp[0], b = xp[1];
    bf16x8 o;
    o[0] = (__bf16)a.x; o[1] = (__bf16)a.y; o[2] = (__bf16)a.z; o[3] = (__bf16)a.w;
    o[4] = (__bf16)b.x; o[5] = (__bf16)b.y; o[6] = (__bf16)b.z; o[7] = (__bf16)b.w;
    ((bf16x8*)xb)[i] = o;
}

// ---------------------------------------------------------------------------
// K0b: embed [256][8192] -> embedT bf16 [8192][256] + embedT fp32 [8192][256]
// ---------------------------------------------------------------------------
__global__ __launch_bounds__(256) void cvt_e_kernel(const float* __restrict__ embed,
                                                    ushort* __restrict__ eb16,
                                                    float* __restrict__ ebT32) {
    __shared__ float tile[64][65];
    const int c00 = blockIdx.x * 64;   // code tile
    const int k0  = blockIdx.y * 64;   // k tile
    const int t   = threadIdx.x;
    const int tc  = t & 63, tr4 = t >> 6;
    #pragma unroll
    for (int i = 0; i < 16; ++i) {
        int r = i * 4 + tr4;
        tile[r][tc] = embed[(size_t)(k0 + r) * NCODE + c00 + tc];
    }
    __syncthreads();
    const int cl = t >> 2;            // local code 0..63
    const int kq = t & 3;             // k quarter (16 each)
    float vals[16];
    #pragma unroll
    for (int j = 0; j < 16; ++j) vals[j] = tile[kq * 16 + j][cl];
    float* d32 = ebT32 + (size_t)(c00 + cl) * DIM + k0 + kq * 16;
    #pragma unroll
    for (int j = 0; j < 4; ++j)
        *(float4*)(d32 + j * 4) = make_float4(vals[j*4], vals[j*4+1], vals[j*4+2], vals[j*4+3]);
    bf16x8 h0, h1;
    #pragma unroll
    for (int j = 0; j < 8; ++j) { h0[j] = (__bf16)vals[j]; h1[j] = (__bf16)vals[8 + j]; }
    ushort* d16 = eb16 + (size_t)(c00 + cl) * DIM + k0 + kq * 16;
    *(bf16x8*)d16 = h0;
    *(bf16x8*)(d16 + 8) = h1;
}

// ---------------------------------------------------------------------------
// K0c: e2[j] exact (validated round-1 chain)
// ---------------------------------------------------------------------------
__global__ __launch_bounds__(256) void e2_kernel(const float* __restrict__ embed,
                                                 float* __restrict__ e2) {
    int j = blockIdx.x * 256 + threadIdx.x;
    float s = 0.f;
    for (int k = 0; k < DIM; ++k) {
        float v = embed[(size_t)k * NCODE + j];
        s = __fadd_rn(s, __fmul_rn(v, v));
    }
    e2[j] = s;
}

// ---------------------------------------------------------------------------
// K1: bf16 MFMA GEMM (scores = e2 - 2*S) + per-row top2 per 128-col chunk.
// m97 structure: 128x128 tile, 4 waves (2x2 of 64x64), BK=32, dbuf LDS,
// global_load_lds width 16, linear LDS layout.
// ---------------------------------------------------------------------------
__global__ __launch_bounds__(256) void gemm_top2_kernel(
    const ushort* __restrict__ xb,   // [NROWS][256] bf16
    const ushort* __restrict__ eb,   // [NCODE][256] bf16 (embed^T)
    const float* __restrict__ e2,    // [NCODE]
    uint4* __restrict__ scratch)     // [NROWS][64]
{
    __shared__ ushort As[2][4096];   // [buf][128 rows * 32 k]
    __shared__ ushort Bs[2][4096];

    const int t    = threadIdx.x;
    const int c0   = blockIdx.x * 128;
    const int r0   = blockIdx.y * 128;
    const int wid  = t >> 6, lane = t & 63;
    const int wr   = wid >> 1, wc = wid & 1;
    const int lr   = lane & 15, g = lane >> 4;

    auto stage = [&](int buf, int ks) {
        #pragma unroll
        for (int i = 0; i < 2; ++i) {
            int o   = t * 16 + i * 4096;      // byte offset in tile
            int row = o >> 6;
            int s   = (o >> 4) & 3;
            gload_lds16(xb + (size_t)(r0 + row) * DIM + ks * 32 + s * 8, &As[buf][o >> 1]);
        }
        #pragma unroll
        for (int i = 0; i < 2; ++i) {
            int o   = t * 16 + i * 4096;
            int row = o >> 6;
            int s   = (o >> 4) & 3;
            gload_lds16(eb + (size_t)(c0 + row) * DIM + ks * 32 + s * 8, &Bs[buf][o >> 1]);
        }
    };

    f32x4 acc[4][4];
    #pragma unroll
    for (int a = 0; a < 4; ++a)
        #pragma unroll
        for (int b = 0; b < 4; ++b) acc[a][b] = (f32x4){0.f, 0.f, 0.f, 0.f};

    stage(0, 0);
    int cur = 0;
    for (int ks = 0; ks < 8; ++ks) {
        __syncthreads();                       // drains staged loads of buf[cur]
        if (ks < 7) stage(cur ^ 1, ks + 1);    // async prefetch next tile
        bf16x8 af[4], bfr[4];
        const char* Ab = (const char*)&As[cur][0];
        const char* Bb = (const char*)&Bs[cur][0];
        #pragma unroll
        for (int fr = 0; fr < 4; ++fr) {
            int row = wr * 64 + fr * 16 + lr;
            af[fr] = *(const bf16x8*)(Ab + row * 64 + g * 16);
        }
        #pragma unroll
        for (int fc = 0; fc < 4; ++fc) {
            int code = wc * 64 + fc * 16 + lr;
            bfr[fc] = *(const bf16x8*)(Bb + code * 64 + g * 16);
        }
        #pragma unroll
        for (int fr = 0; fr < 4; ++fr)
            #pragma unroll
            for (int fc = 0; fc < 4; ++fc)
                acc[fr][fc] = __builtin_amdgcn_mfma_f32_16x16x32_bf16(
                    af[fr], bfr[fc], acc[fr][fc], 0, 0, 0);
        cur ^= 1;
    }

    // ---- epilogue: per-row top2 over this block's 128 cols ----
    __syncthreads();                  // all waves done with tile LDS; reuse as scratch
    uint4* ldsT = (uint4*)&As[0][0];  // [4 waves][64 rows]

    float e2v[4];
    #pragma unroll
    for (int fc = 0; fc < 4; ++fc) e2v[fc] = e2[c0 + wc * 64 + fc * 16 + lr];

    #pragma unroll
    for (int fr = 0; fr < 4; ++fr) {
        #pragma unroll
        for (int reg = 0; reg < 4; ++reg) {
            float v0 = __builtin_inff(), v1 = __builtin_inff();
            int   i0 = -1, i1 = -1;
            #pragma unroll
            for (int fc = 0; fc < 4; ++fc) {
                float sv = __builtin_fmaf(-2.f, acc[fr][fc][reg], e2v[fc]);
                top2_insert(v0, i0, v1, i1, sv, c0 + wc * 64 + fc * 16 + lr);
            }
            #pragma unroll
            for (int m = 1; m < 16; m <<= 1) {
                float b0 = __shfl_xor(v0, m), b1 = __shfl_xor(v1, m);
                int  bi0 = __shfl_xor(i0, m), bi1 = __shfl_xor(i1, m);
                top2_merge(v0, i0, v1, i1, b0, bi0, b1, bi1);
            }
            if (lr == 0)
                ldsT[wid * 64 + fr * 16 + g * 4 + reg] =
                    make_uint4(__float_as_uint(v0), (unsigned)i0,
                               __float_as_uint(v1), (unsigned)i1);
        }
    }
    __syncthreads();
    if (t < 128) {
        int wrh = t >> 6, rl = t & 63;
        uint4 A = ldsT[(wrh * 2 + 0) * 64 + rl];
        uint4 B = ldsT[(wrh * 2 + 1) * 64 + rl];
        float v0 = __uint_as_float(A.x), v1 = __uint_as_float(A.z);
        int   i0 = (int)A.y,             i1 = (int)A.w;
        top2_merge(v0, i0, v1, i1, __uint_as_float(B.x), (int)B.y,
                   __uint_as_float(B.z), (int)B.w);
        scratch[(size_t)(r0 + t) * 64 + blockIdx.x] =
            make_uint4(__float_as_uint(v0), (unsigned)i0,
                       __float_as_uint(v1), (unsigned)i1);
    }
}

// ---------------------------------------------------------------------------
// K2: per-row band candidate capture. One wave per row over 64 chunk entries.
// ---------------------------------------------------------------------------
__global__ __launch_bounds__(256) void band_kernel(
    const uint4* __restrict__ scratch,
    unsigned* __restrict__ lists, unsigned* __restrict__ counts)
{
    const int row  = blockIdx.x * 4 + (threadIdx.x >> 6);
    const int lane = threadIdx.x & 63;
    uint4 e = scratch[(size_t)row * 64 + lane];
    float v0 = __uint_as_float(e.x), v1 = __uint_as_float(e.z);
    float m = v0;
    #pragma unroll
    for (int s = 1; s < 64; s <<= 1) m = fminf(m, __shfl_xor(m, s));
    const float thr = m + 1.0f;      // BAND >= 2*max|bf16 err| (empirical ~20 sigma)
    bool f0 = v0 <= thr, f1 = v1 <= thr;
    unsigned long long b0 = __ballot(f0);
    unsigned long long b1 = __ballot(f1);
    int c0 = __popcll(b0);
    int p0 = __popcll(b0 & ((1ull << lane) - 1));
    int p1 = c0 + __popcll(b1 & ((1ull << lane) - 1));
    if (f0 && p0 < 16) lists[(size_t)row * 16 + p0] = e.y;
    if (f1 && p1 < 16) lists[(size_t)row * 16 + p1] = e.w;
    if (lane == 0) counts[row] = (unsigned)min(c0 + __popcll(b1), 16);
}

// ---------------------------------------------------------------------------
// K3: exact fp32 rescore of candidates (bit-identical round-1 chain).
// 16 slots per row; 16 rows per block.
// ---------------------------------------------------------------------------
__global__ __launch_bounds__(256) void rescore_kernel(
    const float* __restrict__ x, const float* __restrict__ ebT32,
    const float* __restrict__ e2, const unsigned* __restrict__ lists,
    const unsigned* __restrict__ counts, unsigned* __restrict__ best_idx)
{
    const int t    = threadIdx.x;
    const int row  = blockIdx.x * 16 + (t >> 4);
    const int slot = t & 15;
    const int cnt  = (int)counts[row];
    float d = __builtin_inff();
    unsigned idx = 0xFFFFFFFFu;
    if (slot < cnt) {
        idx = lists[(size_t)row * 16 + slot];
        const float* xr = x + (size_t)row * DIM;
        const float* er = ebT32 + (size_t)idx * DIM;
        float f2 = 0.f, dot = 0.f;
        for (int k = 0; k < DIM; ++k) {
            float xv = xr[k];
            f2  = __fadd_rn(f2, __fmul_rn(xv, xv));
            dot = __builtin_fmaf(xv, er[k], dot);
        }
        d = __fadd_rn(__builtin_fmaf(-2.f, dot, f2), e2[idx]);
    }
    #pragma unroll
    for (int m = 1; m < 16; m <<= 1) {
        float    od = __shfl_xor(d, m);
        unsigned oi = (unsigned)__shfl_xor((int)idx, m);
        if (od < d || (od == d && oi < idx)) { d = od; idx = oi; }
    }
    if (slot == 0) best_idx[row] = idx;
}

// ---------------------------------------------------------------------------
// K4: gather + straight-through + diff + ind  (coalesced via ebT32)
// ---------------------------------------------------------------------------
__global__ __launch_bounds__(256) void output_kernel(
    const float* __restrict__ x, const float* __restrict__ ebT32,
    const unsigned* __restrict__ best_idx,
    float* __restrict__ quant, float* __restrict__ diff, float* __restrict__ ind)
{
    const int row = blockIdx.x;
    const int d   = threadIdx.x;
    const unsigned idx = best_idx[row];

    float xv = x[(size_t)row * DIM + d];
    float q  = ebT32[(size_t)idx * DIM + d];
    float dq = __fsub_rn(q, xv);
    quant[(size_t)row * DIM + d] = __fadd_rn(xv, dq);

    float c = __fmul_rn(dq, dq);
    #pragma unroll
    for (int off = 32; off >= 1; off >>= 1) c += __shfl_down(c, off);

    __shared__ float partial[4];
    if ((d & 63) == 0) partial[d >> 6] = c;
    __syncthreads();
    if (d == 0) {
        float s = (partial[0] + partial[1]) + (partial[2] + partial[3]);
        atomicAdd(diff, s * (1.25f / 4194304.f));
        ind[row] = (float)idx;
    }
}

// ---------------------------------------------------------------------------
extern "C" void kernel_launch(void* const* d_in, const int* in_sizes, int n_in,
                              void* d_out, int out_size, void* d_ws, size_t ws_size,
                              hipStream_t stream)
{
    const float* x     = (const float*)d_in[0];   // [16384,256]
    const float* embed = (const float*)d_in[1];   // [256,8192]

    float* out   = (float*)d_out;
    float* quant = out;
    float* diff  = out + 4194304;
    float* ind   = out + 4194305;

    // workspace layout (22.2 MB)
    char* w = (char*)d_ws;
    ushort*   xb      = (ushort*)(w);                     //  8 MB
    ushort*   eb16    = (ushort*)(w + 8388608);           //  4 MB
    float*    ebT32   = (float*) (w + 12582912);          //  8 MB
    float*    e2      = (float*) (w + 20971520);          // 32 KB
    unsigned* lists   = (unsigned*)(w + 21004288);        //  1 MB
    unsigned* counts  = (unsigned*)(w + 22052864);        // 64 KB
    unsigned* bestidx = (unsigned*)(w + 22118400);        // 64 KB

    // top2 scratch overlays the quantize region (exactly 16 MB), freed by K4.
    uint4* scratch = (uint4*)quant;

    cvt_x_kernel<<<2048, 256, 0, stream>>>(x, xb);
    cvt_e_kernel<<<dim3(128, 4), 256, 0, stream>>>(embed, eb16, ebT32);
    e2_kernel<<<32, 256, 0, stream>>>(embed, e2);
    gemm_top2_kernel<<<dim3(64, 128), 256, 0, stream>>>(xb, eb16, e2, scratch);
    band_kernel<<<4096, 256, 0, stream>>>(scratch, lists, counts);
    rescore_kernel<<<1024, 256, 0, stream>>>(x, ebT32, e2, lists, counts, bestidx);
    hipMemsetAsync(diff, 0, sizeof(float), stream);
    output_kernel<<<NROWS, 256, 0, stream>>>(x, ebT32, bestidx, quant, diff, ind);
}